// Round 4
// baseline (46585.706 us; speedup 1.0000x reference)
//
#include <hip/hip_runtime.h>
#include <cmath>

// Problem constants
constexpr int B_  = 16;    // batch
constexpr int N_  = 64;    // frames (scan length)
constexpr int K_  = 20;    // objects incl. image slot
constexpr int KM1 = 19;    // objects
constexpr int D_  = 4096;  // input feature dim
constexpr int DO_ = 1024;
constexpr int H_  = 1024;
constexpr int G4_ = 4096;  // 4*H
constexpr int NBLK = 512;  // persistent scan grid (target 2 blocks/CU)

typedef unsigned short u16;
typedef unsigned int   u32;
typedef __attribute__((ext_vector_type(8))) short bf16x8;  // 8 bf16 = 4 VGPR
typedef __attribute__((ext_vector_type(4))) float f32x4;

typedef const void __attribute__((address_space(1)))* gas1_t;
typedef void __attribute__((address_space(3)))* las3_t;

static __device__ __forceinline__ void gll16(const void* g, void* l) {
  // async global->LDS, 16B per lane; LDS dest is wave-uniform base + lane*16
  __builtin_amdgcn_global_load_lds((gas1_t)g, (las3_t)l, 16, 0, 0);
}

static __device__ __forceinline__ float sigmoidf_(float x) {
  return 1.0f / (1.0f + expf(-x));
}

// round-to-nearest-even fp32 -> bf16 bits
static __device__ __forceinline__ u16 bf16rne(float f) {
  u32 u = __float_as_uint(f);
  return (u16)((u + 0x7fffu + ((u >> 16) & 1u)) >> 16);
}

// ---- hang-proof grid barrier over NP enrolled participants ----
// All participants are provably resident (they executed check-in; GPU blocks
// are never preempted), so this cannot deadlock. Watchdog bounds every spin.
static __device__ __forceinline__ void grid_barrier(int* cnt, int* gen, const int NP) {
  __syncthreads();
  if (threadIdx.x == 0) {
    __threadfence();   // release my writes (device scope)
    const int g = __hip_atomic_load(gen, __ATOMIC_RELAXED, __HIP_MEMORY_SCOPE_AGENT);
    const int arrived =
        __hip_atomic_fetch_add(cnt, 1, __ATOMIC_ACQ_REL, __HIP_MEMORY_SCOPE_AGENT);
    if (arrived == NP - 1) {
      __hip_atomic_store(cnt, 0, __ATOMIC_RELAXED, __HIP_MEMORY_SCOPE_AGENT);
      __hip_atomic_fetch_add(gen, 1, __ATOMIC_ACQ_REL, __HIP_MEMORY_SCOPE_AGENT);
    } else {
      const long long t0 = clock64();
      while (__hip_atomic_load(gen, __ATOMIC_ACQUIRE, __HIP_MEMORY_SCOPE_AGENT) == g) {
        __builtin_amdgcn_s_sleep(2);
        if (clock64() - t0 > (1LL << 24)) break;   // degrade, never hang
      }
    }
    __threadfence();   // acquire others' writes
  }
  __syncthreads();
}

// 256-thread (4-wave) block sum reduction
static __device__ __forceinline__ float block_reduce_sum256(float v, float* red) {
  #pragma unroll
  for (int off = 32; off > 0; off >>= 1) v += __shfl_down(v, off);
  const int wid = threadIdx.x >> 6;
  if ((threadIdx.x & 63) == 0) red[wid] = v;
  __syncthreads();
  const float r = red[0] + red[1] + red[2] + red[3];
  __syncthreads();
  return r;
}

// obj_mask[r] = sum_d x[b, n, 1+kk, d],  r = (b*N + n)*19 + kk
__global__ __launch_bounds__(256) void mask_kernel(const float* __restrict__ x,
                                                   float* __restrict__ mask) {
  const int r = blockIdx.x;
  const int g = r / KM1, kk = r - g * KM1;
  const float4* xp = (const float4*)(x + ((size_t)g * K_ + 1 + kk) * D_);
  float v = 0.f;
  #pragma unroll
  for (int it = 0; it < 4; ++it) {
    const float4 t = xp[threadIdx.x + it * 256];
    v += (t.x + t.y) + (t.z + t.w);
  }
  __shared__ float red[4];
  const float s = block_reduce_sum256(v, red);
  if (threadIdx.x == 0) mask[r] = s;
}

// fp32[r][c] (row stride ld) -> hi/lo bf16 split, same layout [r][c]
__global__ __launch_bounds__(256) void conv_kernel(
    const float* __restrict__ src, const int ld, const int cols,
    u16* __restrict__ oh, u16* __restrict__ ol)
{
  const int id = blockIdx.x * 256 + threadIdx.x;
  const int r = id / (cols >> 2), q = id - r * (cols >> 2);
  const float4 v = *(const float4*)(src + (size_t)r * ld + q * 4);
  const float vv[4] = {v.x, v.y, v.z, v.w};
  u16 h[4], lo[4];
  #pragma unroll
  for (int j = 0; j < 4; ++j) {
    h[j] = bf16rne(vv[j]);
    lo[j] = bf16rne(vv[j] - __uint_as_float((u32)h[j] << 16));
  }
  const size_t o = (size_t)r * cols + q * 4;
  *(ushort4*)(oh + o) = make_ushort4(h[0], h[1], h[2], h[3]);
  *(ushort4*)(ol + o) = make_ushort4(lo[0], lo[1], lo[2], lo[3]);
}

// fp32 [R][C] -> transposed hi/lo bf16 [C][R]
__global__ __launch_bounds__(256) void tconv_kernel(
    const float* __restrict__ src, const int R, const int C,
    u16* __restrict__ oh, u16* __restrict__ ol)
{
  __shared__ float st[64][68];
  const int t = threadIdx.x;
  const int r0 = blockIdx.y * 64, c0 = blockIdx.x * 64;
  const int lr = t >> 4, lc4 = (t & 15) * 4;
  #pragma unroll
  for (int i = 0; i < 4; ++i) {
    const float4 v = *(const float4*)(src + (size_t)(r0 + lr + 16 * i) * C + c0 + lc4);
    st[lr + 16 * i][lc4 + 0] = v.x; st[lr + 16 * i][lc4 + 1] = v.y;
    st[lr + 16 * i][lc4 + 2] = v.z; st[lr + 16 * i][lc4 + 3] = v.w;
  }
  __syncthreads();
  #pragma unroll
  for (int i = 0; i < 4; ++i) {
    const int s = t + 256 * i;
    const int c = s & 63, rq = s >> 6;   // 64 cols x 16 row-quads
    u16 h[4], lo[4];
    #pragma unroll
    for (int j = 0; j < 4; ++j) {
      const float f = st[rq * 4 + j][c];
      h[j] = bf16rne(f);
      lo[j] = bf16rne(f - __uint_as_float((u32)h[j] << 16));
    }
    const size_t o = (size_t)(c0 + c) * R + r0 + rq * 4;
    *(ushort4*)(oh + o) = make_ushort4(h[0], h[1], h[2], h[3]);
    *(ushort4*)(ol + o) = make_ushort4(lo[0], lo[1], lo[2], lo[3]);
  }
}

// bf[n] = sum_j b_obj[j] * W2[j][n]
__global__ __launch_bounds__(256) void bf_kernel(
    const float* __restrict__ b1, const float* __restrict__ W2, float* __restrict__ bf)
{
  const int n = blockIdx.x * 256 + threadIdx.x;
  float acc = 0.f;
  for (int j = 0; j < 1024; ++j) acc = fmaf(b1[j], W2[(size_t)j * 1024 + n], acc);
  bf[n] = acc;
}

// ---------------------------------------------------------------------------
// bf16x3 MFMA GEMM (unchanged, verified passing): C = Ah*Bh + Ah*Bl + Al*Bh
// ---------------------------------------------------------------------------
template<int AMODE, int EPI>
__global__ __launch_bounds__(256, 2) void mfma_gemm(
    const float* __restrict__ Af,
    const u16* __restrict__ Ah, const u16* __restrict__ Al,
    const u16* __restrict__ Bh, const u16* __restrict__ Bl,
    const float* __restrict__ bias, const float* __restrict__ bias2,
    const float* __restrict__ scale,
    float* __restrict__ Cf, u16* __restrict__ Coh, u16* __restrict__ Col,
    const int Kk, const int Nn)
{
  __shared__ alignas(16) char sm[32768];   // A: [0,16K), B: [16K,32K)
  const int t = threadIdx.x;
  const int m0 = blockIdx.x * 128, n0 = blockIdx.y * 128;
  const int w = t >> 6, l = t & 63;
  const int wm = w >> 1, wn = w & 1;

  const int srow = t >> 3;          // staging row (+32*i)
  const int sc16 = (t & 7) * 16;    // 16B chunk within 128B row

  const u16* bsrc[4]; int bdst[4];
  #pragma unroll
  for (int i = 0; i < 4; ++i) {
    const int row = srow + 32 * i;
    const int clog = sc16 ^ ((row & 7) << 4);
    const u16* base = (clog & 64) ? Bl : Bh;
    bsrc[i] = base + (size_t)(n0 + row) * Kk + ((clog & 63) >> 1);
    bdst[i] = 16384 + row * 128 + sc16;
  }

  const float* aptr[4]; int awhi[4], awlo[4];
  const u16* asrc[4]; int adst[4];
  if (AMODE == 0) {
    #pragma unroll
    for (int i = 0; i < 4; ++i) {
      const int row = srow + 32 * i;
      const int clog = sc16 ^ ((row & 7) << 4);
      const u16* base = (clog & 64) ? Al : Ah;
      asrc[i] = base + (size_t)(m0 + row) * Kk + ((clog & 63) >> 1);
      adst[i] = row * 128 + sc16;
    }
  } else {
    #pragma unroll
    for (int i = 0; i < 4; ++i) {
      const int row = srow + 32 * i;
      const int gr = m0 + row;
      size_t roff;
      if (AMODE == 1) { const int g = gr / 19, kk = gr - g * 19;
                        roff = (size_t)(g * 20 + 1 + kk) * 4096; }
      else            { roff = (size_t)gr * (20 * 4096); }
      aptr[i] = Af + roff + (t & 7) * 4;
      const int swz = (row & 7) << 4;
      awhi[i] = row * 128 + (((t & 7) * 8) ^ swz);
      awlo[i] = row * 128 + ((((t & 7) * 8) + 64) ^ swz);
    }
  }

  const int lk16 = (l >> 4) * 16;
  int aoh[4], aol[4], boh[4], bol[4];
  #pragma unroll
  for (int f = 0; f < 4; ++f) {
    const int ar = wm * 64 + f * 16 + (l & 15);
    const int sa = (ar & 7) << 4;
    aoh[f] = ar * 128 + (lk16 ^ sa);
    aol[f] = ar * 128 + ((lk16 + 64) ^ sa);
    const int br = wn * 64 + f * 16 + (l & 15);
    const int sb = (br & 7) << 4;
    boh[f] = 16384 + br * 128 + (lk16 ^ sb);
    bol[f] = 16384 + br * 128 + ((lk16 + 64) ^ sb);
  }

  f32x4 acc[4][4] = {};
  const int nk = Kk >> 5;
  for (int kt = 0; kt < nk; ++kt) {
    #pragma unroll
    for (int i = 0; i < 4; ++i) gll16(bsrc[i] + kt * 32, sm + bdst[i]);
    if (AMODE == 0) {
      #pragma unroll
      for (int i = 0; i < 4; ++i) gll16(asrc[i] + kt * 32, sm + adst[i]);
    } else {
      #pragma unroll
      for (int i = 0; i < 4; ++i) {
        const float4 v = *(const float4*)(aptr[i] + kt * 32);
        const u32 u0 = __float_as_uint(v.x), u1 = __float_as_uint(v.y);
        const u32 u2 = __float_as_uint(v.z), u3 = __float_as_uint(v.w);
        const u32 h01 = (u0 >> 16) | (u1 & 0xffff0000u);
        const u32 h23 = (u2 >> 16) | (u3 & 0xffff0000u);
        const float l0 = v.x - __uint_as_float(u0 & 0xffff0000u);
        const float l1 = v.y - __uint_as_float(u1 & 0xffff0000u);
        const float l2 = v.z - __uint_as_float(u2 & 0xffff0000u);
        const float l3 = v.w - __uint_as_float(u3 & 0xffff0000u);
        const u32 lo01 = (__float_as_uint(l0) >> 16) | (__float_as_uint(l1) & 0xffff0000u);
        const u32 lo23 = (__float_as_uint(l2) >> 16) | (__float_as_uint(l3) & 0xffff0000u);
        *(uint2*)(sm + awhi[i]) = make_uint2(h01, h23);
        *(uint2*)(sm + awlo[i]) = make_uint2(lo01, lo23);
      }
    }
    __syncthreads();

    bf16x8 ah[4], alo[4], bh[4], blo[4];
    #pragma unroll
    for (int f = 0; f < 4; ++f) {
      ah[f]  = *(const bf16x8*)(sm + aoh[f]);
      alo[f] = *(const bf16x8*)(sm + aol[f]);
      bh[f]  = *(const bf16x8*)(sm + boh[f]);
      blo[f] = *(const bf16x8*)(sm + bol[f]);
    }
    #pragma unroll
    for (int mi = 0; mi < 4; ++mi)
      #pragma unroll
      for (int ni = 0; ni < 4; ++ni) {
        acc[mi][ni] = __builtin_amdgcn_mfma_f32_16x16x32_bf16(ah[mi],  bh[ni],  acc[mi][ni], 0, 0, 0);
        acc[mi][ni] = __builtin_amdgcn_mfma_f32_16x16x32_bf16(ah[mi],  blo[ni], acc[mi][ni], 0, 0, 0);
        acc[mi][ni] = __builtin_amdgcn_mfma_f32_16x16x32_bf16(alo[mi], bh[ni],  acc[mi][ni], 0, 0, 0);
      }
    __syncthreads();
  }

  #pragma unroll
  for (int mi = 0; mi < 4; ++mi) {
    const int gr0 = m0 + wm * 64 + mi * 16 + ((l >> 4) << 2);
    #pragma unroll
    for (int ni = 0; ni < 4; ++ni) {
      const int gc = n0 + wn * 64 + ni * 16 + (l & 15);
      const float bb = bias ? bias[gc] : 0.0f;
      const float b2v = (EPI == 2) ? bias2[gc] : 0.0f;
      const f32x4 v = acc[mi][ni];
      #pragma unroll
      for (int r = 0; r < 4; ++r) {
        const int gr = gr0 + r;
        const size_t o = (size_t)gr * Nn + gc;
        if (EPI == 0) {
          Cf[o] = v[r] + bb;
        } else if (EPI == 1) {
          const float fv = v[r] + bb;
          const u16 h = bf16rne(fv);
          Coh[o] = h;
          Col[o] = bf16rne(fv - __uint_as_float((u32)h << 16));
        } else {
          Cf[o] = scale[gr] * (v[r] + bb) + b2v;
        }
      }
    }
  }
}

// ---------------------------------------------------------------------------
// Persistent scan kernel, residency-adaptive: blocks enroll via ticket;
// ticket 0 closes enrollment at present==NBLK or timeout; NP participants
// run all 64 steps with job-loops (j = rid; j < NJOBS; j += NP) and a
// deadlock-free barrier over NP. Math identical to the R1-passing scan.
// bar layout: [0]=cnt [1]=gen [2]=present [3]=closed [4]=np_final
// ---------------------------------------------------------------------------

static __device__ __forceinline__ void gates_job(
    const int job, const int t, char* smem,
    const float* __restrict__ x0, const float* __restrict__ x1,
    const float* __restrict__ W0, const int ld0, const int co0,
    const float* __restrict__ W1, const int ld1, const int co1,
    float* __restrict__ gp)
{
  float (*Ws)[132] = (float(*)[132])smem;                    // [32][132] 16.9KB
  float (*Xs)[20]  = (float(*)[20])(smem + 32 * 132 * 4);    // [32][20]
  const int gc = job & 31, ks = job >> 5;
  const int half = ks >> 3, koff = (ks & 7) * 128;
  const float* X = half ? x1 : x0;
  const float* W = half ? W1 : W0;
  const int ld = half ? ld1 : ld0, co = half ? co1 : co0;
  const int g0 = gc * 128;
  const int tb = t >> 4, tg = (t & 15) * 8;   // thread: 1 b x 8 g
  const int srow = t >> 3, schunk = (t & 7) * 4;
  const float* wbase = W + (size_t)(g0 + srow) * ld + co + koff + schunk;
  float acc[8] = {};
  for (int k0 = 0; k0 < 128; k0 += 32) {
    #pragma unroll
    for (int it = 0; it < 4; ++it) {
      const float4 v = *(const float4*)(wbase + (size_t)it * 32 * ld + k0);
      const int gr = srow + it * 32;
      Ws[schunk + 0][gr] = v.x; Ws[schunk + 1][gr] = v.y;
      Ws[schunk + 2][gr] = v.z; Ws[schunk + 3][gr] = v.w;
    }
    if (t < 128) {
      const int xb = t & 15, xkq = (t >> 4) * 4;
      const float4 v = *(const float4*)(X + (size_t)xb * H_ + koff + k0 + xkq);
      Xs[xkq + 0][xb] = v.x; Xs[xkq + 1][xb] = v.y;
      Xs[xkq + 2][xb] = v.z; Xs[xkq + 3][xb] = v.w;
    }
    __syncthreads();
    #pragma unroll
    for (int k = 0; k < 32; ++k) {
      float wv[8];
      *(float4*)&wv[0] = *(const float4*)&Ws[k][tg];
      *(float4*)&wv[4] = *(const float4*)&Ws[k][tg + 4];
      const float xv = Xs[k][tb];
      #pragma unroll
      for (int gi = 0; gi < 8; ++gi) acc[gi] = fmaf(wv[gi], xv, acc[gi]);
    }
    __syncthreads();
  }
  float* op = gp + ((size_t)ks * B_ + tb) * G4_ + g0 + tg;
  *(float4*)(op)     = *(const float4*)&acc[0];
  *(float4*)(op + 4) = *(const float4*)&acc[4];
}

__global__ __launch_bounds__(256, 2) void scan_kernel(
    const float* __restrict__ a_buf, const float* __restrict__ mask,
    const float* __restrict__ Wah, const float* __restrict__ wj,
    const float* __restrict__ W_ih0, const float* __restrict__ W_hh0,
    const float* __restrict__ W_ih1, const float* __restrict__ W_hh1,
    const float* __restrict__ img_gates, const float* __restrict__ b1v,
    const float* __restrict__ Wout, const float* __restrict__ bout,
    float* __restrict__ ahp, float* __restrict__ wobj,
    float* __restrict__ hA, float* __restrict__ cA,
    float* __restrict__ hB, float* __restrict__ cB,
    float* __restrict__ pred_acc, float* __restrict__ gp,
    int* __restrict__ bar, float* __restrict__ out)
{
  __shared__ alignas(16) char smem[19520];
  __shared__ float redA[4];
  __shared__ int s_rid, s_np;
  const int t = threadIdx.x;
  int* cnt = bar;
  int* gen = bar + 1;

  // ---- enrollment (hang-proof) ----
  if (t == 0) {
    int* present = bar + 2;
    int* closed  = bar + 3;
    int* npf     = bar + 4;
    const int ticket =
        __hip_atomic_fetch_add(present, 1, __ATOMIC_ACQ_REL, __HIP_MEMORY_SCOPE_AGENT);
    int np = 0;
    if (ticket == 0) {
      const long long t0 = clock64();
      while (__hip_atomic_load(present, __ATOMIC_ACQUIRE, __HIP_MEMORY_SCOPE_AGENT) < NBLK
             && clock64() - t0 < (1LL << 24))
        __builtin_amdgcn_s_sleep(2);
      __hip_atomic_store(closed, 1, __ATOMIC_RELEASE, __HIP_MEMORY_SCOPE_AGENT);
      np = __hip_atomic_load(present, __ATOMIC_ACQUIRE, __HIP_MEMORY_SCOPE_AGENT);
      if (np > NBLK) np = NBLK;
      __hip_atomic_store(npf, np, __ATOMIC_RELEASE, __HIP_MEMORY_SCOPE_AGENT);
    } else {
      const long long t0 = clock64();
      while (__hip_atomic_load(closed, __ATOMIC_ACQUIRE, __HIP_MEMORY_SCOPE_AGENT) == 0
             && clock64() - t0 < (1LL << 25))
        __builtin_amdgcn_s_sleep(2);
      const long long t1 = clock64();
      while ((np = __hip_atomic_load(npf, __ATOMIC_ACQUIRE, __HIP_MEMORY_SCOPE_AGENT)) == 0
             && clock64() - t1 < (1LL << 24))
        __builtin_amdgcn_s_sleep(1);
      if (np == 0) np = 1;   // degraded: non-closers bail out below
    }
    s_rid = ticket; s_np = np;
  }
  __syncthreads();
  const int rid = s_rid;
  const int NP  = s_np;
  if (rid >= NP) return;     // late blocks exit; participants are resident

  for (int n = 0; n < N_; ++n) {
    // ---- P1: attn-h partials  ahp[isl][b][j] = sum_{i in 32-slice} hB[b][i]*Wah[i][j]
    for (int job = rid; job < 512; job += NP) {
      const int jc = job & 15, isl = job >> 4;   // 16 j-chunks x 32 i-slices
      float* hbs = (float*)smem;                  // [16][32]
      for (int q = t; q < 512; q += 256)
        hbs[q] = hB[(q >> 5) * H_ + isl * 32 + (q & 31)];
      __syncthreads();
      const int j = jc * 64 + (t & 63), b0 = t >> 6;
      float acc[4] = {};
      for (int i = 0; i < 32; ++i) {
        const float w = Wah[(size_t)(isl * 32 + i) * DO_ + j];
        #pragma unroll
        for (int q = 0; q < 4; ++q)
          acc[q] = fmaf(hbs[(b0 + q * 4) * 32 + i], w, acc[q]);
      }
      #pragma unroll
      for (int q = 0; q < 4; ++q)
        ahp[((size_t)isl * B_ + b0 + q * 4) * DO_ + j] = acc[q];
      __syncthreads();   // smem reuse safety
    }
    grid_barrier(cnt, gen, NP);

    // ---- P2: scores + softmax + w_obj (16 jobs, one per b)
    for (int b = rid; b < B_; b += NP) {
      float* ahs = (float*)smem;        // 1024
      float* wjs = ahs + 1024;          // 1024
      float* sc  = wjs + 1024;          // 20
      const size_t rowbase = (size_t)(b * N_ + n) * KM1;
      #pragma unroll
      for (int it = 0; it < 4; ++it) {
        const int j = t + it * 256;
        float s = 0.f;
        #pragma unroll
        for (int sl = 0; sl < 32; ++sl) s += ahp[((size_t)sl * B_ + b) * DO_ + j];
        ahs[j] = s;
        wjs[j] = wj[j];
      }
      __syncthreads();
      const int w = t >> 6, lane = t & 63;
      for (int k = w; k < KM1; k += 4) {
        const float* ar = a_buf + (rowbase + k) * DO_;
        float v = 0.f;
        #pragma unroll
        for (int it = 0; it < 16; ++it) {
          const int j = lane + it * 64;
          v = fmaf(tanhf(ahs[j] + ar[j]), wjs[j], v);
        }
        #pragma unroll
        for (int off = 32; off > 0; off >>= 1) v += __shfl_down(v, off);
        if (lane == 0) sc[k] = v * mask[rowbase + k];
      }
      __syncthreads();
      float mx = -1e30f;
      #pragma unroll
      for (int k = 0; k < KM1; ++k) mx = fmaxf(mx, sc[k]);
      float al[KM1], ssum = 0.f;
      #pragma unroll
      for (int k = 0; k < KM1; ++k) { al[k] = expf(sc[k] - mx); ssum += al[k]; }
      const float inv = 1.0f / ssum;
      if (t < KM1)
        out[(size_t)n * (B_ * KM1) + b * KM1 + t] = expf(sc[t] - mx) * inv;
      #pragma unroll
      for (int it = 0; it < 4; ++it) {
        const int j = t + it * 256;
        float acc = 0.f;
        #pragma unroll
        for (int k = 0; k < KM1; ++k)
          acc = fmaf(al[k], a_buf[(rowbase + k) * DO_ + j], acc);
        wobj[b * DO_ + j] = acc * inv;
      }
      __syncthreads();   // smem reuse safety
    }
    grid_barrier(cnt, gen, NP);

    // ---- P3: gates0 = [wobj | hA] @ [W_ih0[:,1024:2048] | W_hh0]^T
    for (int job = rid; job < 512; job += NP)
      gates_job(job, t, smem, wobj, hA, W_ih0, 2048, 1024, W_hh0, 1024, 0, gp);
    grid_barrier(cnt, gen, NP);

    // ---- P4: cell0 (64 jobs)
    for (int job = rid; job < 64; job += NP) {
      const int idx = job * 256 + t;
      const int b = idx >> 10, j = idx & 1023;
      const float* ig = img_gates + ((size_t)(b * N_ + n)) * G4_;
      float gi = ig[j], gf = ig[1024 + j], gg = ig[2048 + j], go = ig[3072 + j];
      #pragma unroll
      for (int s = 0; s < 16; ++s) {
        const float* p = gp + ((size_t)s * B_ + b) * G4_;
        gi += p[j]; gf += p[1024 + j]; gg += p[2048 + j]; go += p[3072 + j];
      }
      const float c = cA[idx];
      const float cn = sigmoidf_(gf) * c + sigmoidf_(gi) * tanhf(gg);
      const float hn = sigmoidf_(go) * tanhf(cn);
      cA[idx] = cn; hA[idx] = hn;
    }
    grid_barrier(cnt, gen, NP);

    // ---- P5: gates1 = [hA | hB] @ [W_ih1 | W_hh1]^T
    for (int job = rid; job < 512; job += NP)
      gates_job(job, t, smem, hA, hB, W_ih1, 1024, 0, W_hh1, 1024, 0, gp);
    grid_barrier(cnt, gen, NP);

    // ---- P6: cell1 + pred partial (64 jobs)
    for (int job = rid; job < 64; job += NP) {
      const int b = job >> 2, jq = job & 3;
      const int j = jq * 256 + t;
      float gi = b1v[j], gf = b1v[1024 + j], gg = b1v[2048 + j], go = b1v[3072 + j];
      #pragma unroll
      for (int s = 0; s < 16; ++s) {
        const float* p = gp + ((size_t)s * B_ + b) * G4_;
        gi += p[j]; gf += p[1024 + j]; gg += p[2048 + j]; go += p[3072 + j];
      }
      const int idx = b * H_ + j;
      const float c = cB[idx];
      const float cn = sigmoidf_(gf) * c + sigmoidf_(gi) * tanhf(gg);
      const float hn = sigmoidf_(go) * tanhf(cn);
      cB[idx] = cn; hB[idx] = hn;
      const float part = hn * Wout[j];
      const float s = block_reduce_sum256(part, redA);
      if (t == 0) atomicAdd(&pred_acc[n * B_ + b], s);
    }
    grid_barrier(cnt, gen, NP);
  }

  // ---- final preds (after last barrier, pred_acc complete) ----
  if (rid == 0) {
    const float bo = bout[0];
    float* outp = out + (size_t)N_ * B_ * KM1;
    #pragma unroll
    for (int it = 0; it < 4; ++it) {
      const int i = t + it * 256;
      outp[i] = 1.0f / (1.0f + expf(-(pred_acc[i] + bo)));
    }
  }
}

extern "C" void kernel_launch(void* const* d_in, const int* in_sizes, int n_in,
                              void* d_out, int out_size, void* d_ws, size_t ws_size,
                              hipStream_t stream) {
  const float* x       = (const float*)d_in[0];
  const float* W_img   = (const float*)d_in[1];
  const float* b_img   = (const float*)d_in[2];
  const float* W_obj   = (const float*)d_in[3];
  const float* b_obj   = (const float*)d_in[4];
  const float* W_obj2  = (const float*)d_in[5];
  const float* b_obj2  = (const float*)d_in[6];
  const float* W_attn_h= (const float*)d_in[7];
  const float* W_attn_j= (const float*)d_in[8];
  const float* W_ih0   = (const float*)d_in[9];    // (4096, 2048)
  const float* W_hh0   = (const float*)d_in[10];   // (4096, 1024)
  const float* b0      = (const float*)d_in[11];
  const float* W_ih1   = (const float*)d_in[12];
  const float* W_hh1   = (const float*)d_in[13];
  const float* b1      = (const float*)d_in[14];
  const float* W_out   = (const float*)d_in[15];
  const float* b_out   = (const float*)d_in[16];
  float* out = (float*)d_out;

  // workspace layout: byte-identical to the R1-passing version
  float* ws = (float*)d_ws;
  float* mask     = ws;                                   // 19456
  char*  rA       = (char*)(mask + 19456);                // 19456*1024 floats
  float* a_buf    = (float*)(rA + (size_t)19456 * 4096);  // 19456*1024 floats
  float* ahp_old  = a_buf + (size_t)19456 * 1024;         // (unused slot)
  float* wobj     = ahp_old + 8 * B_ * DO_;               // 16*1024
  float* hA       = wobj + B_ * DO_;
  float* cA       = hA + B_ * H_;
  float* hB       = cA + B_ * H_;
  float* cB       = hB + B_ * H_;
  float* pred_acc = cB + B_ * H_;                         // 1024 (N*B)
  float* gp       = pred_acc + N_ * B_;                   // 16*16*4096

  // conversion buffers inside regionA (76.0 MiB; lifetimes checked):
  const size_t MB = 1u << 20;
  u16* W1c_h   = (u16*)(rA);              // [0,8)   dead after GEMM5
  u16* W1c_l   = (u16*)(rA +  8 * MB);    // [8,16)  dead after GEMM5
  u16* W2t_h   = (u16*)(rA + 16 * MB);    // [16,18) dead after GEMM5
  u16* W2t_l   = (u16*)(rA + 18 * MB);    // [18,20) dead after GEMM5
  u16* Wft_h   = (u16*)(rA + 20 * MB);    // [20,28) dead after GEMM1
  u16* Wft_l   = (u16*)(rA + 28 * MB);    // [28,36) dead after GEMM1
  u16* Wimgt_h = (u16*)(rA + 36 * MB);    // [36,44) dead after GEMM3
  u16* Wimgt_l = (u16*)(rA + 44 * MB);    // [44,52) dead after GEMM3
  u16* Wih0c_h = (u16*)(rA + 52 * MB);    // [52,60) dead after GEMM4
  u16* Wih0c_l = (u16*)(rA + 60 * MB);    // [60,68) dead after GEMM4
  u16* img_h   = (u16*)(rA);              // [0,2)  written by GEMM3 (W1c dead)
  u16* img_l   = (u16*)(rA +  2 * MB);    // [2,4)
  float* img_gates = (float*)(rA + 4 * MB); // [4,20) live during scan
  float* ahp   = (float*)(rA + 24 * MB);  // [24,26) 32*16*1024 floats, scan-only
  float* bfv   = (float*)(rA + 68 * MB);  // 1024 floats
  int*   bar   = (int*)(rA + 72 * MB);    // 8 ints, dead space, scan-only

  // zero LSTM state + pred accumulators; zero barrier/enrollment flags
  hipMemsetAsync(hA, 0, ((size_t)4 * B_ * H_ + N_ * B_) * sizeof(float), stream);
  hipMemsetAsync(bar, 0, 32, stream);

  // ---- feedforward ----
  mask_kernel<<<19456, 256, 0, stream>>>(x, mask);
  conv_kernel<<<4096, 256, 0, stream>>>(W_obj, 1024, 1024, W1c_h, W1c_l);
  tconv_kernel<<<dim3(16, 16), 256, 0, stream>>>(W_obj2, 1024, 1024, W2t_h, W2t_l);
  conv_kernel<<<4096, 256, 0, stream>>>(W_ih0, 2048, 1024, Wih0c_h, Wih0c_l);
  tconv_kernel<<<dim3(16, 64), 256, 0, stream>>>(W_img, 4096, 1024, Wimgt_h, Wimgt_l);
  bf_kernel<<<4, 256, 0, stream>>>(b_obj, W_obj2, bfv);

  // GEMM5: Wft[n][d] = (W_obj @ W_obj2)^T, split output
  mfma_gemm<0, 1><<<dim3(8, 32), 256, 0, stream>>>(
      nullptr, W2t_h, W2t_l, W1c_h, W1c_l,
      nullptr, nullptr, nullptr, nullptr, Wft_h, Wft_l, 1024, 4096);
  // GEMM1 (fused): a[r][n] = mask[r]*((x_r @ Wf)[n] + bf[n]) + b_obj2[n]
  mfma_gemm<1, 2><<<dim3(152, 8), 256, 0, stream>>>(
      x, nullptr, nullptr, Wft_h, Wft_l,
      bfv, b_obj2, mask, a_buf, nullptr, nullptr, 4096, 1024);
  // GEMM3: img_feat = x_img @ W_img + b_img, split output
  mfma_gemm<2, 1><<<dim3(8, 8), 256, 0, stream>>>(
      x, nullptr, nullptr, Wimgt_h, Wimgt_l,
      b_img, nullptr, nullptr, nullptr, img_h, img_l, 4096, 1024);
  // GEMM4: img_gates = img_feat @ W_ih0[:, :1024]^T + b0
  mfma_gemm<0, 0><<<dim3(8, 32), 256, 0, stream>>>(
      nullptr, img_h, img_l, Wih0c_h, Wih0c_l,
      b0, nullptr, nullptr, img_gates, nullptr, nullptr, 1024, 4096);

  // ---- persistent scan (single regular launch, residency-adaptive barrier) ----
  scan_kernel<<<NBLK, 256, 0, stream>>>(
      a_buf, mask, W_attn_h, W_attn_j, W_ih0, W_hh0, W_ih1, W_hh1,
      img_gates, b1, W_out, b_out, ahp, wobj, hA, cA, hB, cB,
      pred_acc, gp, bar, out);
}

// Round 5
// 6342.251 us; speedup vs baseline: 7.3453x; 7.3453x over previous
//
#include <hip/hip_runtime.h>
#include <cmath>

// Problem constants
constexpr int B_  = 16;    // batch
constexpr int N_  = 64;    // frames (scan length)
constexpr int K_  = 20;    // objects incl. image slot
constexpr int KM1 = 19;    // objects
constexpr int D_  = 4096;  // input feature dim
constexpr int DO_ = 1024;
constexpr int H_  = 1024;
constexpr int G4_ = 4096;  // 4*H

typedef unsigned short u16;
typedef unsigned int   u32;
typedef __attribute__((ext_vector_type(8))) short bf16x8;  // 8 bf16 = 4 VGPR
typedef __attribute__((ext_vector_type(4))) float f32x4;

typedef const void __attribute__((address_space(1)))* gas1_t;
typedef void __attribute__((address_space(3)))* las3_t;

static __device__ __forceinline__ void gll16(const void* g, void* l) {
  // async global->LDS, 16B per lane; LDS dest is wave-uniform base + lane*16
  __builtin_amdgcn_global_load_lds((gas1_t)g, (las3_t)l, 16, 0, 0);
}

static __device__ __forceinline__ float sigmoidf_(float x) {
  return 1.0f / (1.0f + expf(-x));
}

// round-to-nearest-even fp32 -> bf16 bits
static __device__ __forceinline__ u16 bf16rne(float f) {
  u32 u = __float_as_uint(f);
  return (u16)((u + 0x7fffu + ((u >> 16) & 1u)) >> 16);
}
static __device__ __forceinline__ float b2f(u16 u) {
  return __uint_as_float((u32)u << 16);
}

// 256-thread (4-wave) block sum reduction
static __device__ __forceinline__ float block_reduce_sum256(float v, float* red) {
  #pragma unroll
  for (int off = 32; off > 0; off >>= 1) v += __shfl_down(v, off);
  const int wid = threadIdx.x >> 6;
  if ((threadIdx.x & 63) == 0) red[wid] = v;
  __syncthreads();
  const float r = red[0] + red[1] + red[2] + red[3];
  __syncthreads();
  return r;
}

// obj_mask[r] = sum_d x[b, n, 1+kk, d],  r = (b*N + n)*19 + kk
__global__ __launch_bounds__(256) void mask_kernel(const float* __restrict__ x,
                                                   float* __restrict__ mask) {
  const int r = blockIdx.x;
  const int g = r / KM1, kk = r - g * KM1;
  const float4* xp = (const float4*)(x + ((size_t)g * K_ + 1 + kk) * D_);
  float v = 0.f;
  #pragma unroll
  for (int it = 0; it < 4; ++it) {
    const float4 t = xp[threadIdx.x + it * 256];
    v += (t.x + t.y) + (t.z + t.w);
  }
  __shared__ float red[4];
  const float s = block_reduce_sum256(v, red);
  if (threadIdx.x == 0) mask[r] = s;
}

// fp32[r][c] (row stride ld) -> hi/lo bf16 split, same layout [r][c], cols from 0
__global__ __launch_bounds__(256) void conv_kernel(
    const float* __restrict__ src, const int ld, const int cols,
    u16* __restrict__ oh, u16* __restrict__ ol)
{
  const int id = blockIdx.x * 256 + threadIdx.x;
  const int r = id / (cols >> 2), q = id - r * (cols >> 2);
  const float4 v = *(const float4*)(src + (size_t)r * ld + q * 4);
  const float vv[4] = {v.x, v.y, v.z, v.w};
  u16 h[4], lo[4];
  #pragma unroll
  for (int j = 0; j < 4; ++j) {
    h[j] = bf16rne(vv[j]);
    lo[j] = bf16rne(vv[j] - __uint_as_float((u32)h[j] << 16));
  }
  const size_t o = (size_t)r * cols + q * 4;
  *(ushort4*)(oh + o) = make_ushort4(h[0], h[1], h[2], h[3]);
  *(ushort4*)(ol + o) = make_ushort4(lo[0], lo[1], lo[2], lo[3]);
}

// fp32 [4096][sld] cols [scol0,scol0+1024) -> hi/lo bf16 [4096][2048] at dcol0
__global__ __launch_bounds__(256) void conv2_kernel(
    const float* __restrict__ src, const int sld, const int scol0,
    u16* __restrict__ dh, u16* __restrict__ dl, const int dcol0)
{
  const int id = blockIdx.x * 256 + threadIdx.x;  // 4096 rows x 256 quads
  const int r = id >> 8, q = id & 255;
  const float4 v = *(const float4*)(src + (size_t)r * sld + scol0 + q * 4);
  const float vv[4] = {v.x, v.y, v.z, v.w};
  u16 h[4], lo[4];
  #pragma unroll
  for (int j = 0; j < 4; ++j) {
    h[j] = bf16rne(vv[j]);
    lo[j] = bf16rne(vv[j] - __uint_as_float((u32)h[j] << 16));
  }
  const size_t o = (size_t)r * 2048 + dcol0 + q * 4;
  *(ushort4*)(dh + o) = make_ushort4(h[0], h[1], h[2], h[3]);
  *(ushort4*)(dl + o) = make_ushort4(lo[0], lo[1], lo[2], lo[3]);
}

// fp32 [R][C] -> transposed hi/lo bf16 [C][R]
__global__ __launch_bounds__(256) void tconv_kernel(
    const float* __restrict__ src, const int R, const int C,
    u16* __restrict__ oh, u16* __restrict__ ol)
{
  __shared__ float st[64][68];
  const int t = threadIdx.x;
  const int r0 = blockIdx.y * 64, c0 = blockIdx.x * 64;
  const int lr = t >> 4, lc4 = (t & 15) * 4;
  #pragma unroll
  for (int i = 0; i < 4; ++i) {
    const float4 v = *(const float4*)(src + (size_t)(r0 + lr + 16 * i) * C + c0 + lc4);
    st[lr + 16 * i][lc4 + 0] = v.x; st[lr + 16 * i][lc4 + 1] = v.y;
    st[lr + 16 * i][lc4 + 2] = v.z; st[lr + 16 * i][lc4 + 3] = v.w;
  }
  __syncthreads();
  #pragma unroll
  for (int i = 0; i < 4; ++i) {
    const int s = t + 256 * i;
    const int c = s & 63, rq = s >> 6;   // 64 cols x 16 row-quads
    u16 h[4], lo[4];
    #pragma unroll
    for (int j = 0; j < 4; ++j) {
      const float f = st[rq * 4 + j][c];
      h[j] = bf16rne(f);
      lo[j] = bf16rne(f - __uint_as_float((u32)h[j] << 16));
    }
    const size_t o = (size_t)(c0 + c) * R + r0 + rq * 4;
    *(ushort4*)(oh + o) = make_ushort4(h[0], h[1], h[2], h[3]);
    *(ushort4*)(ol + o) = make_ushort4(lo[0], lo[1], lo[2], lo[3]);
  }
}

// bf[n] = sum_j b_obj[j] * W2[j][n]
__global__ __launch_bounds__(256) void bf_kernel(
    const float* __restrict__ b1, const float* __restrict__ W2, float* __restrict__ bf)
{
  const int n = blockIdx.x * 256 + threadIdx.x;
  float acc = 0.f;
  for (int j = 0; j < 1024; ++j) acc = fmaf(b1[j], W2[(size_t)j * 1024 + n], acc);
  bf[n] = acc;
}

// ---------------------------------------------------------------------------
// bf16x3 MFMA GEMM (feedforward; verified): C = Ah*Bh + Ah*Bl + Al*Bh
// EPI 0: Cf = acc+bias. EPI 1: split->Coh/Col. EPI 2: scale*(acc+bias)+bias2.
// EPI 3: Coh = bf16(acc+bias) (hi only).
// ---------------------------------------------------------------------------
template<int AMODE, int EPI>
__global__ __launch_bounds__(256, 2) void mfma_gemm(
    const float* __restrict__ Af,
    const u16* __restrict__ Ah, const u16* __restrict__ Al,
    const u16* __restrict__ Bh, const u16* __restrict__ Bl,
    const float* __restrict__ bias, const float* __restrict__ bias2,
    const float* __restrict__ scale,
    float* __restrict__ Cf, u16* __restrict__ Coh, u16* __restrict__ Col,
    const int Kk, const int Nn)
{
  __shared__ alignas(16) char sm[32768];   // A: [0,16K), B: [16K,32K)
  const int t = threadIdx.x;
  const int m0 = blockIdx.x * 128, n0 = blockIdx.y * 128;
  const int w = t >> 6, l = t & 63;
  const int wm = w >> 1, wn = w & 1;

  const int srow = t >> 3;          // staging row (+32*i)
  const int sc16 = (t & 7) * 16;    // 16B chunk within 128B row

  const u16* bsrc[4]; int bdst[4];
  #pragma unroll
  for (int i = 0; i < 4; ++i) {
    const int row = srow + 32 * i;
    const int clog = sc16 ^ ((row & 7) << 4);
    const u16* base = (clog & 64) ? Bl : Bh;
    bsrc[i] = base + (size_t)(n0 + row) * Kk + ((clog & 63) >> 1);
    bdst[i] = 16384 + row * 128 + sc16;
  }

  const float* aptr[4]; int awhi[4], awlo[4];
  const u16* asrc[4]; int adst[4];
  if (AMODE == 0) {
    #pragma unroll
    for (int i = 0; i < 4; ++i) {
      const int row = srow + 32 * i;
      const int clog = sc16 ^ ((row & 7) << 4);
      const u16* base = (clog & 64) ? Al : Ah;
      asrc[i] = base + (size_t)(m0 + row) * Kk + ((clog & 63) >> 1);
      adst[i] = row * 128 + sc16;
    }
  } else {
    #pragma unroll
    for (int i = 0; i < 4; ++i) {
      const int row = srow + 32 * i;
      const int gr = m0 + row;
      size_t roff;
      if (AMODE == 1) { const int g = gr / 19, kk = gr - g * 19;
                        roff = (size_t)(g * 20 + 1 + kk) * 4096; }
      else            { roff = (size_t)gr * (20 * 4096); }
      aptr[i] = Af + roff + (t & 7) * 4;
      const int swz = (row & 7) << 4;
      awhi[i] = row * 128 + (((t & 7) * 8) ^ swz);
      awlo[i] = row * 128 + ((((t & 7) * 8) + 64) ^ swz);
    }
  }

  const int lk16 = (l >> 4) * 16;
  int aoh[4], aol[4], boh[4], bol[4];
  #pragma unroll
  for (int f = 0; f < 4; ++f) {
    const int ar = wm * 64 + f * 16 + (l & 15);
    const int sa = (ar & 7) << 4;
    aoh[f] = ar * 128 + (lk16 ^ sa);
    aol[f] = ar * 128 + ((lk16 + 64) ^ sa);
    const int br = wn * 64 + f * 16 + (l & 15);
    const int sb = (br & 7) << 4;
    boh[f] = 16384 + br * 128 + (lk16 ^ sb);
    bol[f] = 16384 + br * 128 + ((lk16 + 64) ^ sb);
  }

  f32x4 acc[4][4] = {};
  const int nk = Kk >> 5;
  for (int kt = 0; kt < nk; ++kt) {
    #pragma unroll
    for (int i = 0; i < 4; ++i) gll16(bsrc[i] + kt * 32, sm + bdst[i]);
    if (AMODE == 0) {
      #pragma unroll
      for (int i = 0; i < 4; ++i) gll16(asrc[i] + kt * 32, sm + adst[i]);
    } else {
      #pragma unroll
      for (int i = 0; i < 4; ++i) {
        const float4 v = *(const float4*)(aptr[i] + kt * 32);
        const u32 u0 = __float_as_uint(v.x), u1 = __float_as_uint(v.y);
        const u32 u2 = __float_as_uint(v.z), u3 = __float_as_uint(v.w);
        const u32 h01 = (u0 >> 16) | (u1 & 0xffff0000u);
        const u32 h23 = (u2 >> 16) | (u3 & 0xffff0000u);
        const float l0 = v.x - __uint_as_float(u0 & 0xffff0000u);
        const float l1 = v.y - __uint_as_float(u1 & 0xffff0000u);
        const float l2 = v.z - __uint_as_float(u2 & 0xffff0000u);
        const float l3 = v.w - __uint_as_float(u3 & 0xffff0000u);
        const u32 lo01 = (__float_as_uint(l0) >> 16) | (__float_as_uint(l1) & 0xffff0000u);
        const u32 lo23 = (__float_as_uint(l2) >> 16) | (__float_as_uint(l3) & 0xffff0000u);
        *(uint2*)(sm + awhi[i]) = make_uint2(h01, h23);
        *(uint2*)(sm + awlo[i]) = make_uint2(lo01, lo23);
      }
    }
    __syncthreads();

    bf16x8 ah[4], alo[4], bh[4], blo[4];
    #pragma unroll
    for (int f = 0; f < 4; ++f) {
      ah[f]  = *(const bf16x8*)(sm + aoh[f]);
      alo[f] = *(const bf16x8*)(sm + aol[f]);
      bh[f]  = *(const bf16x8*)(sm + boh[f]);
      blo[f] = *(const bf16x8*)(sm + bol[f]);
    }
    #pragma unroll
    for (int mi = 0; mi < 4; ++mi)
      #pragma unroll
      for (int ni = 0; ni < 4; ++ni) {
        acc[mi][ni] = __builtin_amdgcn_mfma_f32_16x16x32_bf16(ah[mi],  bh[ni],  acc[mi][ni], 0, 0, 0);
        acc[mi][ni] = __builtin_amdgcn_mfma_f32_16x16x32_bf16(ah[mi],  blo[ni], acc[mi][ni], 0, 0, 0);
        acc[mi][ni] = __builtin_amdgcn_mfma_f32_16x16x32_bf16(alo[mi], bh[ni],  acc[mi][ni], 0, 0, 0);
      }
    __syncthreads();
  }

  #pragma unroll
  for (int mi = 0; mi < 4; ++mi) {
    const int gr0 = m0 + wm * 64 + mi * 16 + ((l >> 4) << 2);
    #pragma unroll
    for (int ni = 0; ni < 4; ++ni) {
      const int gc = n0 + wn * 64 + ni * 16 + (l & 15);
      const float bb = bias ? bias[gc] : 0.0f;
      const float b2v = (EPI == 2) ? bias2[gc] : 0.0f;
      const f32x4 v = acc[mi][ni];
      #pragma unroll
      for (int r = 0; r < 4; ++r) {
        const int gr = gr0 + r;
        const size_t o = (size_t)gr * Nn + gc;
        if (EPI == 0) {
          Cf[o] = v[r] + bb;
        } else if (EPI == 1) {
          const float fv = v[r] + bb;
          const u16 h = bf16rne(fv);
          Coh[o] = h;
          Col[o] = bf16rne(fv - __uint_as_float((u32)h << 16));
        } else if (EPI == 2) {
          Cf[o] = scale[gr] * (v[r] + bb) + b2v;
        } else {
          Coh[o] = bf16rne(v[r] + bb);
        }
      }
    }
  }
}

// ---------------------------------------------------------------------------
// gemm16: M=16 MFMA partial GEMM for the scan (bf16x3).
// out[(ks*16+b)*LDO + n0+g] = sum_{k in 128-slice ks} X[b][k] * W[n0+g][k]
// X fp32, rows stride 1024; k<KH from x0, else x1 (col k-KH).
// W pre-split bf16 hi/lo, [n][KT] row-major. Grid (NN/64, KT/128).
// LDS: A 16 rows x 128B ([32k hi|32k lo], XOR-swizzled), W 64 rows x 128B.
// ---------------------------------------------------------------------------
__global__ __launch_bounds__(256) void gemm16_kernel(
    const float* __restrict__ x0, const float* __restrict__ x1, const int KH,
    const u16* __restrict__ Wh, const u16* __restrict__ Wl, const int KT,
    float* __restrict__ outp, const int LDO)
{
  __shared__ alignas(16) char sm[2048 + 8192];
  const int t = threadIdx.x;
  const int n0 = blockIdx.x * 64, ks = blockIdx.y;
  const int wv = t >> 6, l = t & 63;

  // W staging (gll16, pre-swizzled source): slots s = t, t+256
  const u16* wsrc[2]; int wdst[2];
  #pragma unroll
  for (int i = 0; i < 2; ++i) {
    const int s = t + 256 * i;
    const int row = s >> 3, phys = (s & 7) * 16;
    const int clog = phys ^ ((row & 7) << 4);
    wsrc[i] = ((clog & 64) ? Wl : Wh) + (size_t)(n0 + row) * KT + ((clog & 63) >> 1);
    wdst[i] = 2048 + s * 16;   // = 2048 + row*128 + phys
  }
  // A staging (threads 0..127): b = t>>3, k-quad = (t&7)*4
  const int ab = t >> 3, akq = (t & 7) * 4;
  const int awhi = ab * 128 + ((akq * 2) ^ ((ab & 7) << 4));

  // fragment read offsets
  const int lk16 = (l >> 4) * 16;
  const int arow = l & 15;
  const int aoh = arow * 128 + (lk16 ^ ((arow & 7) << 4));
  const int wrow = wv * 16 + (l & 15);
  const int boh = 2048 + wrow * 128 + (lk16 ^ ((wrow & 7) << 4));

  f32x4 acc = {};
  #pragma unroll
  for (int kt = 0; kt < 4; ++kt) {
    const int k0 = ks * 128 + kt * 32;
    #pragma unroll
    for (int i = 0; i < 2; ++i) gll16(wsrc[i] + k0, sm + wdst[i]);
    if (t < 128) {
      const float* xs = (k0 < KH) ? (x0 + (size_t)ab * 1024 + k0)
                                  : (x1 + (size_t)ab * 1024 + (k0 - KH));
      const float4 v = *(const float4*)(xs + akq);
      const u32 u0 = __float_as_uint(v.x), u1 = __float_as_uint(v.y);
      const u32 u2 = __float_as_uint(v.z), u3 = __float_as_uint(v.w);
      const u32 h01 = (u0 >> 16) | (u1 & 0xffff0000u);
      const u32 h23 = (u2 >> 16) | (u3 & 0xffff0000u);
      const float l0 = v.x - __uint_as_float(u0 & 0xffff0000u);
      const float l1 = v.y - __uint_as_float(u1 & 0xffff0000u);
      const float l2 = v.z - __uint_as_float(u2 & 0xffff0000u);
      const float l3 = v.w - __uint_as_float(u3 & 0xffff0000u);
      const u32 lo01 = (__float_as_uint(l0) >> 16) | (__float_as_uint(l1) & 0xffff0000u);
      const u32 lo23 = (__float_as_uint(l2) >> 16) | (__float_as_uint(l3) & 0xffff0000u);
      *(uint2*)(sm + awhi) = make_uint2(h01, h23);
      *(uint2*)(sm + (awhi ^ 64)) = make_uint2(lo01, lo23);
    }
    __syncthreads();
    const bf16x8 ah = *(const bf16x8*)(sm + aoh);
    const bf16x8 al = *(const bf16x8*)(sm + (aoh ^ 64));
    const bf16x8 wh = *(const bf16x8*)(sm + boh);
    const bf16x8 wl = *(const bf16x8*)(sm + (boh ^ 64));
    acc = __builtin_amdgcn_mfma_f32_16x16x32_bf16(ah, wh, acc, 0, 0, 0);
    acc = __builtin_amdgcn_mfma_f32_16x16x32_bf16(ah, wl, acc, 0, 0, 0);
    acc = __builtin_amdgcn_mfma_f32_16x16x32_bf16(al, wh, acc, 0, 0, 0);
    __syncthreads();
  }
  // C/D layout: row b = (l>>4)*4 + r, col = l&15
  const int br = (l >> 4) * 2;   // note: (l>>4)<<2 rows; write 4
  (void)br;
  #pragma unroll
  for (int r = 0; r < 4; ++r) {
    const int b = ((l >> 4) << 2) + r;
    outp[((size_t)ks * 16 + b) * LDO + n0 + wv * 16 + (l & 15)] = acc[r];
  }
}

// ---------------------------------------------------------------------------
// Scan cell / attention kernels (discrete launches)
// ---------------------------------------------------------------------------

// scores + softmax + w_obj, one block per b; ahp has 8 k-slice partials
__global__ __launch_bounds__(256) void attn_rest_kernel(
    const float* __restrict__ ahp, const float* __restrict__ a,
    const float* __restrict__ wj, const float* __restrict__ mask,
    const int n, float* __restrict__ alphas_out, float* __restrict__ wobj)
{
  const int b = blockIdx.x, t = threadIdx.x;
  __shared__ float ahs[DO_];
  __shared__ float wjs[DO_];
  __shared__ float sc[KM1 + 1];
  const size_t rowbase = (size_t)(b * N_ + n) * KM1;
  #pragma unroll
  for (int it = 0; it < 4; ++it) {
    const int j = t + it * 256;
    float s = 0.f;
    #pragma unroll
    for (int sl = 0; sl < 8; ++sl) s += ahp[((size_t)sl * B_ + b) * DO_ + j];
    ahs[j] = s;
    wjs[j] = wj[j];
  }
  __syncthreads();
  const int w = t >> 6, lane = t & 63;
  for (int k = w; k < KM1; k += 4) {
    const float* ar = a + (rowbase + k) * DO_;
    float v = 0.f;
    #pragma unroll
    for (int it = 0; it < 16; ++it) {
      const int j = lane + it * 64;
      v = fmaf(tanhf(ahs[j] + ar[j]), wjs[j], v);
    }
    #pragma unroll
    for (int off = 32; off > 0; off >>= 1) v += __shfl_down(v, off);
    if (lane == 0) sc[k] = v * mask[rowbase + k];
  }
  __syncthreads();
  float mx = -1e30f;
  #pragma unroll
  for (int k = 0; k < KM1; ++k) mx = fmaxf(mx, sc[k]);
  float al[KM1], ssum = 0.f;
  #pragma unroll
  for (int k = 0; k < KM1; ++k) { al[k] = expf(sc[k] - mx); ssum += al[k]; }
  const float inv = 1.0f / ssum;
  if (t < KM1) alphas_out[b * KM1 + t] = al[t] * inv;
  #pragma unroll
  for (int it = 0; it < 4; ++it) {
    const int j = t + it * 256;
    float acc = 0.f;
    #pragma unroll
    for (int k = 0; k < KM1; ++k)
      acc = fmaf(al[k], a[(rowbase + k) * DO_ + j], acc);
    wobj[b * DO_ + j] = acc * inv;
  }
}

// layer-0 cell: gates = bf16(img_gates incl b0) + sum of 16 partials
__global__ __launch_bounds__(256) void cell0_kernel(
    const float* __restrict__ gp, const u16* __restrict__ igh, const int n,
    float* __restrict__ hA, float* __restrict__ cA)
{
  const int idx = blockIdx.x * 256 + threadIdx.x;   // 16384 = 16b x 1024j
  const int b = idx >> 10, j = idx & 1023;
  const u16* ig = igh + ((size_t)(b * N_ + n)) * G4_;
  float gi = b2f(ig[j]), gf = b2f(ig[1024 + j]);
  float gg = b2f(ig[2048 + j]), go = b2f(ig[3072 + j]);
  #pragma unroll
  for (int s = 0; s < 16; ++s) {
    const float* p = gp + ((size_t)s * B_ + b) * G4_;
    gi += p[j]; gf += p[1024 + j]; gg += p[2048 + j]; go += p[3072 + j];
  }
  const float c = cA[idx];
  const float cn = sigmoidf_(gf) * c + sigmoidf_(gi) * tanhf(gg);
  const float hn = sigmoidf_(go) * tanhf(cn);
  cA[idx] = cn; hA[idx] = hn;
}

// layer-1 cell; 64 blocks (4 per b); pred partial via atomicAdd
__global__ __launch_bounds__(256) void cell1_kernel(
    const float* __restrict__ gp, const float* __restrict__ b1,
    const float* __restrict__ Wout,
    float* __restrict__ hB, float* __restrict__ cB, float* __restrict__ pred_acc)
{
  const int b = blockIdx.x >> 2, jq = blockIdx.x & 3, tid = threadIdx.x;
  const int j = jq * 256 + tid;
  float gi = b1[j], gf = b1[1024 + j], gg = b1[2048 + j], go = b1[3072 + j];
  #pragma unroll
  for (int s = 0; s < 16; ++s) {
    const float* p = gp + ((size_t)s * B_ + b) * G4_;
    gi += p[j]; gf += p[1024 + j]; gg += p[2048 + j]; go += p[3072 + j];
  }
  const int idx = b * H_ + j;
  const float c = cB[idx];
  const float cn = sigmoidf_(gf) * c + sigmoidf_(gi) * tanhf(gg);
  const float hn = sigmoidf_(go) * tanhf(cn);
  cB[idx] = cn; hB[idx] = hn;
  float part = hn * Wout[j];
  __shared__ float red[4];
  const float s = block_reduce_sum256(part, red);
  if (tid == 0) atomicAdd(&pred_acc[b], s);
}

// final: sigmoid over all (n,b) pred accumulators
__global__ __launch_bounds__(256) void pred_kernel(
    const float* __restrict__ pred_acc, const float* __restrict__ bout,
    float* __restrict__ out_pred)
{
  const float bo = bout[0];
  #pragma unroll
  for (int it = 0; it < 4; ++it) {
    const int i = threadIdx.x + it * 256;
    out_pred[i] = 1.0f / (1.0f + expf(-(pred_acc[i] + bo)));
  }
}

extern "C" void kernel_launch(void* const* d_in, const int* in_sizes, int n_in,
                              void* d_out, int out_size, void* d_ws, size_t ws_size,
                              hipStream_t stream) {
  const float* x       = (const float*)d_in[0];
  const float* W_img   = (const float*)d_in[1];
  const float* b_img   = (const float*)d_in[2];
  const float* W_obj   = (const float*)d_in[3];
  const float* b_obj   = (const float*)d_in[4];
  const float* W_obj2  = (const float*)d_in[5];
  const float* b_obj2  = (const float*)d_in[6];
  const float* W_attn_h= (const float*)d_in[7];
  const float* W_attn_j= (const float*)d_in[8];
  const float* W_ih0   = (const float*)d_in[9];    // (4096, 2048)
  const float* W_hh0   = (const float*)d_in[10];   // (4096, 1024)
  const float* b0      = (const float*)d_in[11];
  const float* W_ih1   = (const float*)d_in[12];
  const float* W_hh1   = (const float*)d_in[13];
  const float* b1      = (const float*)d_in[14];
  const float* W_out   = (const float*)d_in[15];
  const float* b_out   = (const float*)d_in[16];
  float* out = (float*)d_out;

  // workspace layout (base slots byte-identical to the verified R1 layout)
  float* ws = (float*)d_ws;
  float* mask     = ws;                                   // 19456
  char*  rA       = (char*)(mask + 19456);                // 76 MiB region
  float* a_buf    = (float*)(rA + (size_t)19456 * 4096);  // 19456*1024 floats
  float* ahp      = a_buf + (size_t)19456 * 1024;         // 8*16*1024 floats
  float* wobj     = ahp + 8 * B_ * DO_;                   // 16*1024
  float* hA       = wobj + B_ * DO_;
  float* cA       = hA + B_ * H_;
  float* hB       = cA + B_ * H_;
  float* cB       = hB + B_ * H_;
  float* pred_acc = cB + B_ * H_;                         // 1024 (N*B)
  float* gp       = pred_acc + N_ * B_;                   // 16*16*4096

  // regionA sub-buffers (all offsets MiB; lifetimes ordered below):
  const size_t MB = 1u << 20;
  u16* W1c_h   = (u16*)(rA);              // [0,8)   dead after GEMM5
  u16* W1c_l   = (u16*)(rA +  8 * MB);    // [8,16)  dead after GEMM5
  u16* W2t_h   = (u16*)(rA + 16 * MB);    // [16,18) dead after GEMM5
  u16* W2t_l   = (u16*)(rA + 18 * MB);    // [18,20) dead after GEMM5
  u16* Wft_h   = (u16*)(rA + 20 * MB);    // [20,28) dead after GEMM1
  u16* Wft_l   = (u16*)(rA + 28 * MB);    // [28,36) dead after GEMM1
  u16* Wimgt_h = (u16*)(rA + 36 * MB);    // [36,44) dead after GEMM3
  u16* Wimgt_l = (u16*)(rA + 44 * MB);    // [44,52) dead after GEMM3
  u16* Wih0c_h = (u16*)(rA + 52 * MB);    // [52,60) dead after GEMM4
  u16* Wih0c_l = (u16*)(rA + 60 * MB);    // [60,68) dead after GEMM4
  float* bfv   = (float*)(rA + 68 * MB);  // dead after GEMM1
  u16* img_h   = (u16*)(rA + 20 * MB);    // [20,22) written by GEMM3 (Wft dead)
  u16* img_l   = (u16*)(rA + 22 * MB);    // [22,24)
  // scan-persistent (written after GEMM4):
  u16* igh     = (u16*)(rA);              // [0,8)   img gates, bf16 hi
  u16* Wg0h    = (u16*)(rA +  8 * MB);    // [8,24)  [Wih0_obj|Whh0] hi
  u16* Wg0l    = (u16*)(rA + 24 * MB);    // [24,40) lo
  u16* Wg1h    = (u16*)(rA + 40 * MB);    // [40,56) [Wih1|Whh1] hi
  u16* Wg1l    = (u16*)(rA + 56 * MB);    // [56,72) lo
  u16* Waht_h  = (u16*)(rA + 72 * MB);    // [72,74) W_attn_h^T hi
  u16* Waht_l  = (u16*)(rA + 74 * MB);    // [74,76) lo

  // zero LSTM state + pred accumulators
  hipMemsetAsync(hA, 0, ((size_t)4 * B_ * H_ + N_ * B_) * sizeof(float), stream);

  // ---- feedforward ----
  mask_kernel<<<19456, 256, 0, stream>>>(x, mask);
  conv_kernel<<<4096, 256, 0, stream>>>(W_obj, 1024, 1024, W1c_h, W1c_l);
  tconv_kernel<<<dim3(16, 16), 256, 0, stream>>>(W_obj2, 1024, 1024, W2t_h, W2t_l);
  conv_kernel<<<4096, 256, 0, stream>>>(W_ih0, 2048, 1024, Wih0c_h, Wih0c_l);
  tconv_kernel<<<dim3(16, 64), 256, 0, stream>>>(W_img, 4096, 1024, Wimgt_h, Wimgt_l);
  bf_kernel<<<4, 256, 0, stream>>>(b_obj, W_obj2, bfv);

  // GEMM5: Wft[n][d] = (W_obj @ W_obj2)^T, split output
  mfma_gemm<0, 1><<<dim3(8, 32), 256, 0, stream>>>(
      nullptr, W2t_h, W2t_l, W1c_h, W1c_l,
      nullptr, nullptr, nullptr, nullptr, Wft_h, Wft_l, 1024, 4096);
  // GEMM1 (fused): a[r][n] = mask[r]*((x_r @ Wf)[n] + bf[n]) + b_obj2[n]
  mfma_gemm<1, 2><<<dim3(152, 8), 256, 0, stream>>>(
      x, nullptr, nullptr, Wft_h, Wft_l,
      bfv, b_obj2, mask, a_buf, nullptr, nullptr, 4096, 1024);
  // GEMM3: img_feat = x_img @ W_img + b_img, split output (into dead Wft slot)
  mfma_gemm<2, 1><<<dim3(8, 8), 256, 0, stream>>>(
      x, nullptr, nullptr, Wimgt_h, Wimgt_l,
      b_img, nullptr, nullptr, nullptr, img_h, img_l, 4096, 1024);
  // GEMM4: img_gates = bf16hi(img_feat @ W_ih0[:, :1024]^T + b0)
  mfma_gemm<0, 3><<<dim3(8, 32), 256, 0, stream>>>(
      nullptr, img_h, img_l, Wih0c_h, Wih0c_l,
      b0, nullptr, nullptr, nullptr, igh, nullptr, 1024, 4096);

  // scan weight prep (after GEMM4; overwrite dead conversion slots)
  tconv_kernel<<<dim3(16, 16), 256, 0, stream>>>(W_attn_h, 1024, 1024, Waht_h, Waht_l);
  conv2_kernel<<<4096, 256, 0, stream>>>(W_ih0, 2048, 1024, Wg0h, Wg0l, 0);
  conv2_kernel<<<4096, 256, 0, stream>>>(W_hh0, 1024, 0,    Wg0h, Wg0l, 1024);
  conv2_kernel<<<4096, 256, 0, stream>>>(W_ih1, 1024, 0,    Wg1h, Wg1l, 0);
  conv2_kernel<<<4096, 256, 0, stream>>>(W_hh1, 1024, 0,    Wg1h, Wg1l, 1024);

  // ---- sequential scan (discrete launches, MFMA gates) ----
  for (int n = 0; n < N_; ++n) {
    // P1: attn-h partials (8 k-slices): ahp = hB @ Wah
    gemm16_kernel<<<dim3(16, 8), 256, 0, stream>>>(
        hB, hB, 1024, Waht_h, Waht_l, 1024, ahp, 1024);
    // P2: scores + softmax + w_obj
    attn_rest_kernel<<<B_, 256, 0, stream>>>(ahp, a_buf, W_attn_j, mask, n,
                                             out + (size_t)n * (B_ * KM1), wobj);
    // P3: gates0 partials = [wobj | hA] @ Wg0^T
    gemm16_kernel<<<dim3(64, 16), 256, 0, stream>>>(
        wobj, hA, 1024, Wg0h, Wg0l, 2048, gp, 4096);
    // P4: cell0
    cell0_kernel<<<64, 256, 0, stream>>>(gp, igh, n, hA, cA);
    // P5: gates1 partials = [hA | hB] @ Wg1^T
    gemm16_kernel<<<dim3(64, 16), 256, 0, stream>>>(
        hA, hB, 1024, Wg1h, Wg1l, 2048, gp, 4096);
    // P6: cell1 + pred partial
    cell1_kernel<<<64, 256, 0, stream>>>(gp, b1, W_out, hB, cB, pred_acc + n * B_);
  }
  pred_kernel<<<1, 256, 0, stream>>>(pred_acc, b_out, out + (size_t)N_ * B_ * KM1);
}